// Round 3
// baseline (332.872 us; speedup 1.0000x reference)
//
#include <hip/hip_runtime.h>

#define T_TOTAL 4194304
#define BLK 256
#define PER_TH 16
#define CHUNK (BLK * PER_TH)     // 4096 elements per block
#define NB (T_TOTAL / CHUNK)     // 1024 blocks = 4 blocks/CU x 256 CUs exactly
#define NWAVE (BLK / 64)         // 4 waves per block
#define SCOPE __HIP_MEMORY_SCOPE_AGENT

// ws layout (uint words): [0]=arrive counter, [1]=done counter, [2..3]=acc(double),
// then gA[NB], gD[NB] (floats)
__global__ void k_init(unsigned* __restrict__ w) {
    if (threadIdx.x < 4) w[threadIdx.x] = 0u;
}

// Co-residency: 1024 blocks of 256 threads = 4 blocks/CU on 256 CUs.
// __launch_bounds__(256,4) => VGPR<=128 => 4 waves/SIMD => 4 blocks/CU guaranteed.
// LDS 16.5KB (not limiting), 16 waves/CU (not limiting). Grid barrier is safe.
__global__ __launch_bounds__(BLK, 4) void k_vtrace(
    const float* __restrict__ lp, const float* __restrict__ olp,
    const float* __restrict__ val, const float* __restrict__ nval,
    const float* __restrict__ rew, const float* __restrict__ ter,
    unsigned* __restrict__ bar, unsigned* __restrict__ done,
    double* __restrict__ acc,
    float* __restrict__ gA, float* __restrict__ gD,
    float* __restrict__ out)
{
    __shared__ float wA[NWAVE], wD[NWAVE], rsum[NWAVE];
    __shared__ float sv[CHUNK];
    __shared__ float sVin;

    const int t = threadIdx.x;
    const int lane = t & 63;
    const int w = t >> 6;
    const int b = blockIdx.x;                      // chunk index, elements [b*CHUNK, (b+1)*CHUNK)
    const size_t base4 = (size_t)b * (CHUNK / 4) + 4 * (size_t)t;  // thread's 4 contiguous float4s

    // ---- load 16 contiguous elements x 6 arrays, compute a,d ----
    float a[PER_TH], d[PER_TH];
#pragma unroll
    for (int k = 0; k < 4; ++k) {
        const float4 L = ((const float4*)lp)[base4 + k];
        const float4 O = ((const float4*)olp)[base4 + k];
        const float4 V = ((const float4*)val)[base4 + k];
        const float4 N = ((const float4*)nval)[base4 + k];
        const float4 R = ((const float4*)rew)[base4 + k];
        const float4 Tm = ((const float4*)ter)[base4 + k];
        const float Ls[4] = {L.x, L.y, L.z, L.w};
        const float Os[4] = {O.x, O.y, O.z, O.w};
        const float Vs[4] = {V.x, V.y, V.z, V.w};
        const float Ns[4] = {N.x, N.y, N.z, N.w};
        const float Rs[4] = {R.x, R.y, R.z, R.w};
        const float Ts[4] = {Tm.x, Tm.y, Tm.z, Tm.w};
#pragma unroll
        for (int i = 0; i < 4; ++i) {
            const float ratio = __expf(Ls[i] - Os[i]);
            const float rho   = fminf(1.0f, ratio);
            a[4 * k + i] = Ts[i] * rho;
            d[4 * k + i] = rho * (Rs[i] + Ts[i] * Ns[i] - Vs[i]);
        }
    }

    // ---- per-thread serial compose: T = T_e0 o T_e1 o ... (v_left = A*v_right + D) ----
    float A = 1.0f, D = 0.0f;
#pragma unroll
    for (int i = 0; i < PER_TH; ++i) { D = fmaf(A, d[i], D); A *= a[i]; }

    // ---- wave inclusive suffix scan (lane l gets compose of lanes l..63) ----
    float iA = A, iD = D;
#pragma unroll
    for (int s = 1; s < 64; s <<= 1) {
        const float oA = __shfl_down(iA, s);
        const float oD = __shfl_down(iD, s);
        if (lane + s < 64) { iD = fmaf(iA, oD, iD); iA *= oA; }
    }
    if (lane == 0) { wA[w] = iA; wD[w] = iD; }
    __syncthreads();                               // barrier 1

    // suffix over later waves: S_w = W_{w+1} o ... o W_{NWAVE-1}
    float SA = 1.0f, SD = 0.0f;
#pragma unroll
    for (int j = 0; j < NWAVE; ++j) {
        if (j > w) { SD = fmaf(SA, wD[j], SD); SA *= wA[j]; }
    }

    // exclusive-within-wave (lanes l+1..63), composed with later-wave suffix
    float eA = __shfl_down(iA, 1);
    float eD = __shfl_down(iD, 1);
    if (lane == 63) { eA = 1.0f; eD = 0.0f; }
    const float EA = eA * SA;
    const float ED = fmaf(eA, SD, eD);

    // ---- publish block aggregate, grid arrive-barrier ----
    if (t == 0) {
        const float BA = iA * SA;                  // block transform (t==0: w==0, lane==0)
        const float BD = fmaf(iA, SD, iD);
        __hip_atomic_store(&gA[b], BA, __ATOMIC_RELAXED, SCOPE);
        __hip_atomic_store(&gD[b], BD, __ATOMIC_RELAXED, SCOPE);
        __threadfence();                           // make aggregate visible before arrive
        atomicAdd(bar, 1u);                        // device-scope
        while (__hip_atomic_load(bar, __ATOMIC_RELAXED, SCOPE) < NB)
            __builtin_amdgcn_s_sleep(2);
        __threadfence();                           // acquire side
    }
    __syncthreads();                               // barrier 2 (releases whole block)

    // ---- wave 0: carry for this block = compose of aggregates [b+1, NB) applied to 0 ----
    if (w == 0) {
        const int n = NB - 1 - b;
        float cA = 1.0f, cD = 0.0f;
        if (n > 0) {
            const int len = (n + 63) >> 6;         // <=16
            int j0 = b + 1 + lane * len;
            int j1 = j0 + len; if (j1 > NB) j1 = NB;
            for (int j = j0; j < j1; ++j) {
                const float Aj = __hip_atomic_load(&gA[j], __ATOMIC_RELAXED, SCOPE);
                const float Dj = __hip_atomic_load(&gD[j], __ATOMIC_RELAXED, SCOPE);
                cD = fmaf(cA, Dj, cD);
                cA *= Aj;
            }
#pragma unroll
            for (int s = 1; s < 64; s <<= 1) {
                const float oA = __shfl_down(cA, s);
                const float oD = __shfl_down(cD, s);
                if (lane + s < 64) { cD = fmaf(cA, oD, cD); cA *= oA; }
            }
        }
        if (lane == 0) sVin = cD;                  // applied to v=0 => just D
    }
    __syncthreads();                               // barrier 3
    const float vin = sVin;

    // ---- per-thread carry, serial backward recurrence; ys stored in-place over d ----
    float v = fmaf(EA, vin, ED);
    float ss = 0.0f;
#pragma unroll
    for (int i = PER_TH - 1; i >= 0; --i) {
        v = fmaf(a[i], v, d[i]);
        d[i] = v;
        ss = fmaf(v, v, ss);
    }

    // ---- stage ys in LDS, coalesced scalar stores (out+1 misaligned for float4) ----
#pragma unroll
    for (int k = 0; k < 4; ++k)
        ((float4*)sv)[4 * t + k] = make_float4(d[4*k+0], d[4*k+1], d[4*k+2], d[4*k+3]);
    __syncthreads();                               // barrier 4
    const size_t obase = 1 + (size_t)b * CHUNK;
#pragma unroll
    for (int k = 0; k < PER_TH; ++k) out[obase + t + k * BLK] = sv[t + k * BLK];

    // ---- loss: wave butterfly -> LDS -> one atomic/block; last block finalizes ----
#pragma unroll
    for (int s = 32; s > 0; s >>= 1) ss += __shfl_xor(ss, s);
    if (lane == 0) rsum[w] = ss;
    __syncthreads();                               // barrier 5
    if (t == 0) {
        float bs = 0.0f;
#pragma unroll
        for (int j = 0; j < NWAVE; ++j) bs += rsum[j];
        atomicAdd(acc, (double)bs);
        __threadfence();
        const unsigned old = atomicAdd(done, 1u);
        if (old == NB - 1) {
            const double av = __hip_atomic_load(acc, __ATOMIC_ACQUIRE, SCOPE);
            out[0] = (float)(av * (1.0 / (double)T_TOTAL));
        }
    }
}

extern "C" void kernel_launch(void* const* d_in, const int* in_sizes, int n_in,
                              void* d_out, int out_size, void* d_ws, size_t ws_size,
                              hipStream_t stream) {
    const float* lp   = (const float*)d_in[0];
    const float* olp  = (const float*)d_in[1];
    const float* val  = (const float*)d_in[2];
    const float* nval = (const float*)d_in[3];
    const float* rew  = (const float*)d_in[4];
    const float* ter  = (const float*)d_in[5];
    float* out = (float*)d_out;

    unsigned* wsw  = (unsigned*)d_ws;
    unsigned* bar  = wsw + 0;
    unsigned* done = wsw + 1;
    double*   acc  = (double*)(wsw + 2);
    float*    gA   = (float*)(wsw + 4);
    float*    gD   = gA + NB;

    k_init<<<1, 64, 0, stream>>>(wsw);
    k_vtrace<<<NB, BLK, 0, stream>>>(lp, olp, val, nval, rew, ter,
                                     bar, done, acc, gA, gD, out);
}

// Round 4
// 168.334 us; speedup vs baseline: 1.9775x; 1.9775x over previous
//
#include <hip/hip_runtime.h>

#define T_TOTAL 4194304
#define BLK 256
#define PER_TH 8
#define CHUNK (BLK * PER_TH)      // 2048 elements per block
#define NB (T_TOTAL / CHUNK)      // 2048 chunks
#define NWAVE (BLK / 64)          // 4 waves per block
#define SBLK 512                  // k_scan block size
#define SWAVE (SBLK / 64)         // 8 waves
#define SPER (NB / SBLK)          // 4 aggregates per scan thread

// Affine transform convention: T_i maps v_{i+1} -> v_i = a_i*v_{i+1} + d_i.
// Compose over increasing i (fold): D = fmaf(A, d_i, D); A *= a_i.
// Combine adjacent ranges L(lower idx) o R(higher idx): A = A_L*A_R, D = D_L + A_L*D_R.

// ---------------- pass 1: per-chunk aggregate (pure stream) ----------------
__global__ __launch_bounds__(BLK) void k_agg(
    const float* __restrict__ lp, const float* __restrict__ olp,
    const float* __restrict__ val, const float* __restrict__ nval,
    const float* __restrict__ rew, const float* __restrict__ ter,
    float* __restrict__ bA, float* __restrict__ bD)
{
    __shared__ float wA[NWAVE], wD[NWAVE];
    const int b = blockIdx.x, t = threadIdx.x;
    const int lane = t & 63, w = t >> 6;
    const size_t base4 = (size_t)b * (CHUNK / 4) + 2 * (size_t)t;  // 2 float4s/thread

    float A = 1.0f, D = 0.0f;
#pragma unroll
    for (int k = 0; k < 2; ++k) {
        const float4 L = ((const float4*)lp)[base4 + k];
        const float4 O = ((const float4*)olp)[base4 + k];
        const float4 V = ((const float4*)val)[base4 + k];
        const float4 N = ((const float4*)nval)[base4 + k];
        const float4 R = ((const float4*)rew)[base4 + k];
        const float4 Tm = ((const float4*)ter)[base4 + k];
        const float Ls[4] = {L.x, L.y, L.z, L.w};
        const float Os[4] = {O.x, O.y, O.z, O.w};
        const float Vs[4] = {V.x, V.y, V.z, V.w};
        const float Ns[4] = {N.x, N.y, N.z, N.w};
        const float Rs[4] = {R.x, R.y, R.z, R.w};
        const float Ts[4] = {Tm.x, Tm.y, Tm.z, Tm.w};
#pragma unroll
        for (int i = 0; i < 4; ++i) {
            const float rho = fminf(1.0f, __expf(Ls[i] - Os[i]));
            const float ai = Ts[i] * rho;
            const float di = rho * (Rs[i] + Ts[i] * Ns[i] - Vs[i]);
            D = fmaf(A, di, D);
            A *= ai;
        }
    }

    // wave suffix compose -> lane 0 holds wave total
    float iA = A, iD = D;
#pragma unroll
    for (int s = 1; s < 64; s <<= 1) {
        const float oA = __shfl_down(iA, s);
        const float oD = __shfl_down(iD, s);
        if (lane + s < 64) { iD = fmaf(iA, oD, iD); iA *= oA; }
    }
    if (lane == 0) { wA[w] = iA; wD[w] = iD; }
    __syncthreads();
    if (t == 0) {
        float BA = 1.0f, BD = 0.0f;
#pragma unroll
        for (int j = 0; j < NWAVE; ++j) { BD = fmaf(BA, wD[j], BD); BA *= wA[j]; }
        bA[b] = BA; bD[b] = BD;
    }
}

// ---------------- pass 2: scan over 2048 chunk aggregates ----------------
// carry[c] = v at element (c+1)*CHUNK = compose of aggregates c+1..NB-1 applied to 0.
__global__ __launch_bounds__(SBLK) void k_scan(
    const float* __restrict__ bA, const float* __restrict__ bD,
    float* __restrict__ carry, double* __restrict__ acc)
{
    __shared__ float wA[SWAVE], wD[SWAVE];
    const int t = threadIdx.x;
    const int lane = t & 63, w = t >> 6;
    if (t == 0) *acc = 0.0;   // zero loss accumulator (ws is poisoned each launch)

    // thread t composes aggregates [4t, 4t+3]
    float a4[SPER], d4[SPER];
    {
        const float4 A4 = ((const float4*)bA)[t];
        const float4 D4 = ((const float4*)bD)[t];
        a4[0] = A4.x; a4[1] = A4.y; a4[2] = A4.z; a4[3] = A4.w;
        d4[0] = D4.x; d4[1] = D4.y; d4[2] = D4.z; d4[3] = D4.w;
    }
    float A = 1.0f, D = 0.0f;
#pragma unroll
    for (int i = 0; i < SPER; ++i) { D = fmaf(A, d4[i], D); A *= a4[i]; }

    // wave inclusive suffix scan
    float iA = A, iD = D;
#pragma unroll
    for (int s = 1; s < 64; s <<= 1) {
        const float oA = __shfl_down(iA, s);
        const float oD = __shfl_down(iD, s);
        if (lane + s < 64) { iD = fmaf(iA, oD, iD); iA *= oA; }
    }
    if (lane == 0) { wA[w] = iA; wD[w] = iD; }
    __syncthreads();

    // suffix over later waves
    float SA = 1.0f, SD = 0.0f;
#pragma unroll
    for (int j = 0; j < SWAVE; ++j) {
        if (j > w) { SD = fmaf(SA, wD[j], SD); SA *= wA[j]; }
    }

    // exclusive within wave (threads > t in this wave), composed with later waves
    float eA = __shfl_down(iA, 1);
    float eD = __shfl_down(iD, 1);
    if (lane == 63) { eA = 1.0f; eD = 0.0f; }
    const float ED = fmaf(eA, SD, eD);   // applied to v=0 -> only D matters

    // distribute to the 4 chunks: v_edge(4t+3) = ED; v_edge(c-1) = a[c]*v_edge(c)+d[c]
    float c4[SPER];
    float v = ED;
    c4[SPER - 1] = v;
#pragma unroll
    for (int i = SPER - 1; i > 0; --i) { v = fmaf(a4[i], v, d4[i]); c4[i - 1] = v; }
    ((float4*)carry)[t] = make_float4(c4[0], c4[1], c4[2], c4[3]);
}

// ---------------- pass 3: recompute a,d; apply carries; outputs + loss ----------------
__global__ __launch_bounds__(BLK) void k_out(
    const float* __restrict__ lp, const float* __restrict__ olp,
    const float* __restrict__ val, const float* __restrict__ nval,
    const float* __restrict__ rew, const float* __restrict__ ter,
    const float* __restrict__ carry,
    float* __restrict__ out, double* __restrict__ acc)
{
    __shared__ float wA[NWAVE], wD[NWAVE], rsum[NWAVE];
    __shared__ float sv[CHUNK];
    __shared__ float sVin;

    const int b = blockIdx.x, t = threadIdx.x;
    const int lane = t & 63, w = t >> 6;
    const size_t base4 = (size_t)b * (CHUNK / 4) + 2 * (size_t)t;

    float a[PER_TH], d[PER_TH];
#pragma unroll
    for (int k = 0; k < 2; ++k) {
        const float4 L = ((const float4*)lp)[base4 + k];
        const float4 O = ((const float4*)olp)[base4 + k];
        const float4 V = ((const float4*)val)[base4 + k];
        const float4 N = ((const float4*)nval)[base4 + k];
        const float4 R = ((const float4*)rew)[base4 + k];
        const float4 Tm = ((const float4*)ter)[base4 + k];
        const float Ls[4] = {L.x, L.y, L.z, L.w};
        const float Os[4] = {O.x, O.y, O.z, O.w};
        const float Vs[4] = {V.x, V.y, V.z, V.w};
        const float Ns[4] = {N.x, N.y, N.z, N.w};
        const float Rs[4] = {R.x, R.y, R.z, R.w};
        const float Ts[4] = {Tm.x, Tm.y, Tm.z, Tm.w};
#pragma unroll
        for (int i = 0; i < 4; ++i) {
            const float rho = fminf(1.0f, __expf(Ls[i] - Os[i]));
            a[4 * k + i] = Ts[i] * rho;
            d[4 * k + i] = rho * (Rs[i] + Ts[i] * Ns[i] - Vs[i]);
        }
    }

    float A = 1.0f, D = 0.0f;
#pragma unroll
    for (int i = 0; i < PER_TH; ++i) { D = fmaf(A, d[i], D); A *= a[i]; }

    float iA = A, iD = D;
#pragma unroll
    for (int s = 1; s < 64; s <<= 1) {
        const float oA = __shfl_down(iA, s);
        const float oD = __shfl_down(iD, s);
        if (lane + s < 64) { iD = fmaf(iA, oD, iD); iA *= oA; }
    }
    if (lane == 0) { wA[w] = iA; wD[w] = iD; }
    if (t == 0) sVin = carry[b];
    __syncthreads();                               // barrier 1

    float SA = 1.0f, SD = 0.0f;
#pragma unroll
    for (int j = 0; j < NWAVE; ++j) {
        if (j > w) { SD = fmaf(SA, wD[j], SD); SA *= wA[j]; }
    }
    float eA = __shfl_down(iA, 1);
    float eD = __shfl_down(iD, 1);
    if (lane == 63) { eA = 1.0f; eD = 0.0f; }
    const float EA = eA * SA;
    const float ED = fmaf(eA, SD, eD);
    const float vin = sVin;

    // per-thread carry, then serial backward recurrence (ys = v)
    float v = fmaf(EA, vin, ED);
    float ss = 0.0f;
#pragma unroll
    for (int i = PER_TH - 1; i >= 0; --i) {
        v = fmaf(a[i], v, d[i]);
        d[i] = v;
        ss = fmaf(v, v, ss);
    }

    // stage in LDS, coalesced scalar stores (out+1 is 4B-misaligned for float4)
#pragma unroll
    for (int k = 0; k < 2; ++k)
        ((float4*)sv)[2 * t + k] =
            make_float4(d[4*k+0], d[4*k+1], d[4*k+2], d[4*k+3]);
    __syncthreads();                               // barrier 2
    const size_t obase = 1 + (size_t)b * CHUNK;
#pragma unroll
    for (int k = 0; k < PER_TH; ++k) out[obase + t + k * BLK] = sv[t + k * BLK];

    // loss: wave butterfly -> LDS -> one double atomic per block
#pragma unroll
    for (int s = 32; s > 0; s >>= 1) ss += __shfl_xor(ss, s);
    if (lane == 0) rsum[w] = ss;
    __syncthreads();                               // barrier 3
    if (t == 0) {
        float bs = 0.0f;
#pragma unroll
        for (int j = 0; j < NWAVE; ++j) bs += rsum[j];
        atomicAdd(acc, (double)bs);
    }
}

// ---------------- pass 4: finalize loss ----------------
__global__ void k_loss(const double* __restrict__ acc, float* __restrict__ out) {
    out[0] = (float)(*acc * (1.0 / (double)T_TOTAL));
}

extern "C" void kernel_launch(void* const* d_in, const int* in_sizes, int n_in,
                              void* d_out, int out_size, void* d_ws, size_t ws_size,
                              hipStream_t stream) {
    const float* lp   = (const float*)d_in[0];
    const float* olp  = (const float*)d_in[1];
    const float* val  = (const float*)d_in[2];
    const float* nval = (const float*)d_in[3];
    const float* rew  = (const float*)d_in[4];
    const float* ter  = (const float*)d_in[5];
    float* out = (float*)d_out;

    double* acc  = (double*)d_ws;                       // 16B reserved
    float*  bA   = (float*)((char*)d_ws + 16);          // NB floats, 16B aligned
    float*  bD   = bA + NB;
    float*  carry = bD + NB;                            // ws use: 16 + 3*NB*4 = ~24.6 KB

    k_agg <<<NB, BLK, 0, stream>>>(lp, olp, val, nval, rew, ter, bA, bD);
    k_scan<<<1, SBLK, 0, stream>>>(bA, bD, carry, acc);
    k_out <<<NB, BLK, 0, stream>>>(lp, olp, val, nval, rew, ter, carry, out, acc);
    k_loss<<<1, 1, 0, stream>>>(acc, out);
}